// Round 8
// baseline (94.477 us; speedup 1.0000x reference)
//
#include <hip/hip_runtime.h>

// SGAN_PoolingNet: pooled[i] = max_j relu( relu([hidden[j], (ends[j]-ends[i])@We+be] @ W1 + b1) @ W2 + b2 )
// Collapse: y_lin[i,j,:] = A[j,:] - U[i,:]
//   A[j,k] = hidden[j]@W1[0:64,k] + ends[j]@M2[:,k] + b1[k] + be@W1[64:80,k]   (f32 math, stored f16)
//   U[i,k] = ends[i]@M2[:,k],  M2 = We @ W1[64:80,:]  (2x128, f32)
// R11 == R9 mechanism, lambda-restructured (R9/R10 benches were infra failures x2; source
//     audited clean: no OOB, no divergent barrier, no data-dependent loops -> restructure the
//     macro-heavy body into an inlined lambda to hedge a tooling pathology, semantics identical).
//     R8 analysis: total 92.2 = 40.5 fill + ~15-22 prep+overhead + pool(~25-30). Pool is
//     load-latency wait (~1200cy/body vs ~4us issue floor): the 268MB ws-poison fill sweeps
//     L2+L3 each iteration, prep's NT stores land A at L3/HBM, depth-2 coverage ~525cy <
//     L3/HBM-miss (500-900cy). Fix: DEPTH-3 register ring (+16 VGPR, ~220 unified < 256 cap
//     @ 2 waves/SIMD, no spill): coverage ~900cy >= HBM-miss class.

#define N_AG 1024
#define JT 4

typedef __attribute__((ext_vector_type(8))) _Float16 half8;      // 8 f16 = 4 VGPR (MFMA A/B frag)
typedef __attribute__((ext_vector_type(4))) float floatx4;       // MFMA C/D frag
typedef __attribute__((ext_vector_type(4))) unsigned int uintx4; // 4 packed f16 pairs

__device__ __forceinline__ unsigned short f2h(float f) {
  return __builtin_bit_cast(unsigned short, (_Float16)f);   // RNE
}

// d = max(a - u, 0) elementwise on packed f16 pairs: 2 VALU instrs, no unpack.
__device__ __forceinline__ unsigned pk_sub_relu(unsigned a, unsigned u) {
  unsigned d;
  asm("v_pk_add_f16 %0, %1, %2 neg_lo:[0,1] neg_hi:[0,1]\n\t"
      "v_pk_max_f16 %0, %0, 0"
      : "=v"(d) : "v"(a), "v"(u));
  return d;
}

// ---- prep: block jb computes A[4jb..4jb+3]; block 0 writes M2; blocks 0..31 write W2T ----
__global__ __launch_bounds__(128) void prep_all(
    const float* __restrict__ hidden,  // (1,1024,64)
    const float* __restrict__ track,   // (1024,8,2)
    const float* __restrict__ We,      // (2,16)
    const float* __restrict__ be,      // (16)
    const float* __restrict__ W1,      // (80,128)
    const float* __restrict__ b1,      // (128)
    const float* __restrict__ W2,      // (128,64)
    unsigned short* __restrict__ Ah,   // (1024,128) f16
    float* __restrict__ M2f,           // (2,128) f32
    unsigned short* __restrict__ W2T)  // (64,128) f16
{
  const int jb = blockIdx.x;          // 0..255
  const int j0 = jb * JT;
  const int k  = threadIdx.x;         // 0..127
  __shared__ float hs[JT][64];
#pragma unroll
  for (int q = k; q < JT * 64; q += 128) hs[q >> 6][q & 63] = hidden[j0 * 64 + q];
  __syncthreads();

  float m20 = 0.f, m21 = 0.f, cb = b1[k];
#pragma unroll
  for (int t = 0; t < 16; ++t) {
    float w1v = W1[(64 + t) * 128 + k];
    m20 += We[t] * w1v;
    m21 += We[16 + t] * w1v;
    cb  += be[t] * w1v;
  }
  float acc[JT];
#pragma unroll
  for (int jj = 0; jj < JT; ++jj) {
    float e0 = track[(j0 + jj) * 16 + 14];
    float e1 = track[(j0 + jj) * 16 + 15];
    acc[jj] = e0 * m20 + e1 * m21 + cb;
  }
#pragma unroll 8
  for (int t = 0; t < 64; ++t) {
    float w = W1[t * 128 + k];
#pragma unroll
    for (int jj = 0; jj < JT; ++jj) acc[jj] += hs[jj][t] * w;
  }
#pragma unroll
  for (int jj = 0; jj < JT; ++jj)
    __builtin_nontemporal_store(f2h(acc[jj]), &Ah[(j0 + jj) * 128 + k]);

  if (jb == 0) {          // m20/m21 are exactly M2[0][k], M2[1][k]
    M2f[k]       = m20;
    M2f[128 + k] = m21;
  }
  if (jb < 32) {          // W2T[n][c] = f16(W2[c][n]); 32 blocks x 256 entries
#pragma unroll
    for (int q = 0; q < 2; ++q) {
      int idx = jb * 256 + q * 128 + k;
      int n = idx >> 7, c = idx & 127;
      W2T[n * 128 + c] = f2h(W2[c * 64 + n]);
    }
  }
}

// ---- main: one block per 2 agents; 4 waves split j 4-way (disjoint), each full 64 cols ----
__global__ __launch_bounds__(256, 2) void pool_main(
    const unsigned short* __restrict__ Ah,    // (1024,128) f16
    const float* __restrict__ M2f,            // (2,128) f32
    const float* __restrict__ track,          // (1024,8,2) f32
    const unsigned short* __restrict__ W2T,   // (64,128) f16
    const float* __restrict__ b2,             // (64) f32
    float* __restrict__ out)                  // (1024,64) f32
{
  const int i0   = blockIdx.x * 2;
  const int lane = threadIdx.x & 63;
  const int w    = threadIdx.x >> 6;   // wave 0..3: j-tiles jt = 4t + w
  const int m    = lane & 15;          // A row within tile / B-and-D column
  const int quad = lane >> 4;          // k-subrange selector

  const int TSTEP = 4 * 16 * 128;      // elems between this wave's consecutive tiles
  const unsigned short* base = Ah + (w * 16 + m) * 128 + quad * 8;

  // depth-3 register ring: issue tiles 0,1,2 of this wave ASAP
  uintx4 buf0[4], buf1[4], buf2[4];
#pragma unroll
  for (int kk = 0; kk < 4; ++kk) buf0[kk] = *(const uintx4*)(base + kk * 32);
#pragma unroll
  for (int kk = 0; kk < 4; ++kk) buf1[kk] = *(const uintx4*)(base + TSTEP + kk * 32);
#pragma unroll
  for (int kk = 0; kk < 4; ++kk) buf2[kk] = *(const uintx4*)(base + 2 * TSTEP + kk * 32);

  // U[i0], U[i0+1] as packed f16 pairs matching A's dword element order
  const float a0 = track[i0 * 16 + 14];
  const float a1 = track[i0 * 16 + 15];
  const float c0 = track[(i0 + 1) * 16 + 14];
  const float c1 = track[(i0 + 1) * 16 + 15];
  unsigned upkA[4][4], upkB[4][4];
#pragma unroll
  for (int kk = 0; kk < 4; ++kk) {
#pragma unroll
    for (int p = 0; p < 4; ++p) {
      int k0 = kk * 32 + quad * 8 + 2 * p;
      float m0 = M2f[k0],     m0h = M2f[128 + k0];
      float m1 = M2f[k0 + 1], m1h = M2f[128 + k0 + 1];
      upkA[kk][p] = (unsigned)f2h(a0 * m0 + a1 * m0h) | ((unsigned)f2h(a0 * m1 + a1 * m1h) << 16);
      upkB[kk][p] = (unsigned)f2h(c0 * m0 + c1 * m0h) | ((unsigned)f2h(c0 * m1 + c1 * m1h) << 16);
    }
  }

  // full 64-col B panel per wave (4 x 16-col blocks), register/AGPR-resident
  half8 bfrag[4][4];
#pragma unroll
  for (int nt = 0; nt < 4; ++nt)
#pragma unroll
    for (int kk = 0; kk < 4; ++kk)
      bfrag[nt][kk] = *(const half8*)(W2T + (nt * 16 + m) * 128 + kk * 32 + quad * 8);

  floatx4 mxA[4], mxB[4];
#pragma unroll
  for (int nt = 0; nt < 4; ++nt) {
    mxA[nt] = (floatx4){-3e38f, -3e38f, -3e38f, -3e38f};
    mxB[nt] = (floatx4){-3e38f, -3e38f, -3e38f, -3e38f};
  }

  const unsigned short* pn = base + 3 * TSTEP;   // next tile to load (t+3)

  // body: repack+MFMA both agents for tile in BUF; optionally prefetch tile at pn.
  auto body = [&](uintx4 (&BUF)[4], bool do_load) {
    uintx4 au[4];
#pragma unroll
    for (int kk = 0; kk < 4; ++kk)
#pragma unroll
      for (int p = 0; p < 4; ++p) au[kk][p] = pk_sub_relu(BUF[kk][p], upkA[kk][p]);
#pragma unroll
    for (int nt = 0; nt < 4; ++nt) {
      floatx4 acc = (floatx4){0.f, 0.f, 0.f, 0.f};
#pragma unroll
      for (int kk = 0; kk < 4; ++kk)
        acc = __builtin_amdgcn_mfma_f32_16x16x32_f16(
            __builtin_bit_cast(half8, au[kk]), bfrag[nt][kk], acc, 0, 0, 0);
#pragma unroll
      for (int r = 0; r < 4; ++r) mxA[nt][r] = fmaxf(mxA[nt][r], acc[r]);
    }
#pragma unroll
    for (int kk = 0; kk < 4; ++kk)
#pragma unroll
      for (int p = 0; p < 4; ++p) au[kk][p] = pk_sub_relu(BUF[kk][p], upkB[kk][p]);
    if (do_load) {
#pragma unroll
      for (int kk = 0; kk < 4; ++kk) BUF[kk] = *(const uintx4*)(pn + kk * 32);
      pn += TSTEP;
    }
#pragma unroll
    for (int nt = 0; nt < 4; ++nt) {
      floatx4 acc = (floatx4){0.f, 0.f, 0.f, 0.f};
#pragma unroll
      for (int kk = 0; kk < 4; ++kk)
        acc = __builtin_amdgcn_mfma_f32_16x16x32_f16(
            __builtin_bit_cast(half8, au[kk]), bfrag[nt][kk], acc, 0, 0, 0);
#pragma unroll
      for (int r = 0; r < 4; ++r) mxB[nt][r] = fmaxf(mxB[nt][r], acc[r]);
    }
  };

  // 16 tiles/wave, depth-3 ring: 4x{b0,b1,b2} loading t+3 (t=0..11 -> loads 3..14),
  // then tail t=12 (loads 15), t=13, t=14, t=15 (no loads).
#pragma unroll 1
  for (int t3 = 0; t3 < 4; ++t3) {
    body(buf0, true);
    body(buf1, true);
    body(buf2, true);
  }
  body(buf0, true);    // t=12, loads t=15 into buf0
  body(buf1, false);   // t=13
  body(buf2, false);   // t=14
  body(buf0, false);   // t=15

  // D layout: row = quad*4 + r (j within tile), col = nt*16 + m. Reduce rows in-lane,
  // across quads via shfl, across the 4 j-waves via LDS. Two agents' results side by side.
  __shared__ float red[2][4][64];
#pragma unroll
  for (int nt = 0; nt < 4; ++nt) {
    float a = fmaxf(fmaxf(mxA[nt][0], mxA[nt][1]), fmaxf(mxA[nt][2], mxA[nt][3]));
    a = fmaxf(a, __shfl_xor(a, 16, 64));
    a = fmaxf(a, __shfl_xor(a, 32, 64));
    float b = fmaxf(fmaxf(mxB[nt][0], mxB[nt][1]), fmaxf(mxB[nt][2], mxB[nt][3]));
    b = fmaxf(b, __shfl_xor(b, 16, 64));
    b = fmaxf(b, __shfl_xor(b, 32, 64));
    if (quad == 0) {
      red[0][w][nt * 16 + m] = a;
      red[1][w][nt * 16 + m] = b;
    }
  }
  __syncthreads();
  if (threadIdx.x < 128) {
    int g = threadIdx.x >> 6, n = threadIdx.x & 63;
    float v = fmaxf(fmaxf(red[g][0][n], red[g][1][n]), fmaxf(red[g][2][n], red[g][3][n]));
    v += b2[n];
    out[(i0 + g) * 64 + n] = v > 0.f ? v : 0.f;
  }
}

extern "C" void kernel_launch(void* const* d_in, const int* in_sizes, int n_in,
                              void* d_out, int out_size, void* d_ws, size_t ws_size,
                              hipStream_t stream) {
  const float* hidden = (const float*)d_in[0]; // (1,1024,64)
  const float* track  = (const float*)d_in[1]; // (1024,8,2)
  const float* We     = (const float*)d_in[2]; // (2,16)
  const float* be     = (const float*)d_in[3]; // (16)
  const float* W1     = (const float*)d_in[4]; // (80,128)
  const float* b1     = (const float*)d_in[5]; // (128)
  const float* W2     = (const float*)d_in[6]; // (128,64)
  const float* b2     = (const float*)d_in[7]; // (64)
  float* out = (float*)d_out;

  char* ws = (char*)d_ws;
  unsigned short* Ah  = (unsigned short*)ws;              // 1024*128*2 = 256 KiB
  float*          M2f = (float*)(ws + 262144);            // 256*4     = 1 KiB
  unsigned short* W2T = (unsigned short*)(ws + 263168);   // 64*128*2  = 16 KiB

  prep_all<<<N_AG / JT, 128, 0, stream>>>(hidden, track, We, be, W1, b1, W2, Ah, M2f, W2T);
  pool_main<<<N_AG / 2, 256, 0, stream>>>(Ah, M2f, track, W2T, b2, out);
}